// Round 4
// baseline (1914.179 us; speedup 1.0000x reference)
//
#include <hip/hip_runtime.h>
#include <hip/hip_cooperative_groups.h>

namespace cg = cooperative_groups;

#define B_ 128
#define T_ 20
#define V_ 10000
#define H_ 512
#define F_ 49
#define NWG 128

typedef unsigned short u16;
typedef __attribute__((ext_vector_type(8))) short short8;
typedef __attribute__((ext_vector_type(4))) float floatx4;

#define GLOBAL_AS __attribute__((address_space(1)))
#define LDS_AS    __attribute__((address_space(3)))

__device__ inline void load_lds16(const void* g, void* l) {
    __builtin_amdgcn_global_load_lds((const GLOBAL_AS void*)g, (LDS_AS void*)l, 16, 0, 0);
}

// fp32 -> bf16 round-to-nearest-even
__device__ inline u16 f2b(float v) {
    unsigned u = __builtin_bit_cast(unsigned, v);
    unsigned rounding = 0x7FFFu + ((u >> 16) & 1u);
    return (u16)((u + rounding) >> 16);
}
__device__ inline float b2f(u16 h) {
    unsigned u = ((unsigned)h) << 16;
    return __builtin_bit_cast(float, u);
}
__device__ inline float fast_tanh(float x) {
    return 1.f - 2.f / (__expf(2.f * x) + 1.f);
}
__device__ inline float sigm(float x) { return 1.f / (1.f + __expf(-x)); }

// ================= prep: all setup work in ONE kernel (block-range dispatch) =========
__device__ inline void transpose_body(const float* __restrict__ src, u16* __restrict__ dst,
                                      int K, int N, int bx, int by, int tid) {
    __shared__ float tile[32][33];
    int n0 = bx * 32, k0 = by * 32;
    int tx = tid & 31, ty = tid >> 5;    // 32 x 8
    #pragma unroll
    for (int i = 0; i < 32; i += 8) {
        int k = k0 + ty + i, n = n0 + tx;
        tile[ty + i][tx] = (k < K && n < N) ? src[(size_t)k * N + n] : 0.f;
    }
    __syncthreads();
    #pragma unroll
    for (int i = 0; i < 32; i += 8) {
        int n = n0 + ty + i, k = k0 + tx;
        if (n < N && k < K) dst[(size_t)n * K + k] = f2b(tile[tx][ty + i]);
    }
}

// block ranges:
//  [0,2048)       WihT   (K=1024,N=2048) nx=64
//  [2048,3072)    WhhT   (K=512, N=2048) nx=64
//  [3072,3328)    WvT    (512,512)       nx=16
//  [3328,3584)    WhT    (512,512)       nx=16
//  [3584,13600)   WoutT  (K=1024,N=10000) nx=313
//  [13600,16160)  build_x  2560
//  [16160,28704)  feat_cvt 12544
//  [28704,28960)  init hb0
__global__ __launch_bounds__(256) void prep(
        const float* __restrict__ W_ih, u16* __restrict__ WihT,
        const float* __restrict__ W_hh, u16* __restrict__ WhhT,
        const float* __restrict__ Wv,   u16* __restrict__ WvT,
        const float* __restrict__ Wh,   u16* __restrict__ WhT,
        const float* __restrict__ W_out,u16* __restrict__ WoutT,
        const int* __restrict__ cap, const float* __restrict__ emb,
        const float* __restrict__ gf, u16* __restrict__ X,
        const float* __restrict__ area, u16* __restrict__ feat,
        const float* __restrict__ h0, u16* __restrict__ hb0) {
    const int blk = blockIdx.x, tid = threadIdx.x;
    if (blk < 2048) {
        transpose_body(W_ih, WihT, 1024, 2048, blk % 64, blk / 64, tid);
    } else if (blk < 3072) {
        int r = blk - 2048; transpose_body(W_hh, WhhT, 512, 2048, r % 64, r / 64, tid);
    } else if (blk < 3328) {
        int r = blk - 3072; transpose_body(Wv, WvT, 512, 512, r % 16, r / 16, tid);
    } else if (blk < 3584) {
        int r = blk - 3328; transpose_body(Wh, WhT, 512, 512, r % 16, r / 16, tid);
    } else if (blk < 13600) {
        int r = blk - 3584; transpose_body(W_out, WoutT, 1024, 10000, r % 313, r / 313, tid);
    } else if (blk < 16160) {
        int r = blk - 13600;               // r = t*128 + b
        int t = r / B_, b = r % B_;
        int tok = cap[b * T_ + t];
        for (int col = tid; col < 2 * H_; col += 256) {
            float v = (col < H_) ? emb[(size_t)tok * H_ + col]
                                 : gf[(size_t)b * H_ + (col - H_)];
            X[(size_t)r * (2 * H_) + col] = f2b(v);
        }
    } else if (blk < 28704) {
        int idx = (blk - 16160) * 256 + tid;    // < 128*49*512 = 3211264
        if (idx < B_ * F_ * H_) {
            int h = idx & (H_ - 1);
            int bf_ = idx >> 9;
            int f = bf_ % F_, b = bf_ / F_;
            feat[idx] = f2b(area[((size_t)b * H_ + h) * F_ + f]);
        }
    } else {
        int idx = (blk - 28704) * 256 + tid;    // < 65536
        hb0[idx] = f2b(h0[idx]);
    }
}

// ================= persistent sequential loop: 1 cooperative launch, 20 steps ========
// grid 128 WGs x 256 threads. Per step:
//   P1: gates = h@W_hh + Xin[t] (M=128 MFMA; WG w owns cols {g*512 + w*4 + jj}) + LSTM.
//       c-state lives in LDS for the whole kernel. Writes h(bf16) -> hb[(t+1)&1].
//   grid.sync()
//   P23: per-b attention (WG b): ah = h@Wh, scores, softmax, attended, Hcat row.
// One sync/step suffices: P23(t) reads hb[(t+1)&1]; P1(t+1) writes hb[t&1] (disjoint).
__global__ __launch_bounds__(256) void seq_loop(
        const u16* __restrict__ WhhT,    // [2048][512]
        const u16* __restrict__ WhT,     // [512][512]
        const u16* __restrict__ Vprojb,  // [128*49][512]
        const float* __restrict__ wo,    // [512]
        const u16* __restrict__ feat,    // [128*49][512]
        const float* __restrict__ Xin,   // [20*128][2048] (biases included)
        const float* __restrict__ c0,    // [128][512]
        u16* __restrict__ hb,            // [2][128][512]; hb[0] pre-initialized
        u16* __restrict__ Hcat) {        // [2560][1024]
    cg::grid_group grid = cg::this_grid();
    const int w = blockIdx.x;
    const int tid = threadIdx.x, wave = tid >> 6, lane = tid & 63;
    const int lm = lane & 15, q = lane >> 4;

    __shared__ float cs[512];     // c state: [b][jj] -> b*4+jj (this WG's j-slice)
    __shared__ float gl[2048];    // gates staging: g*512 + b*4 + jj
    __shared__ float hsh[H_], ash[H_], wosh[H_];
    __shared__ float sc[64];

    for (int i = tid; i < 512; i += 256)
        cs[i] = c0[(size_t)(i >> 2) * H_ + w * 4 + (i & 3)];
    for (int i = tid; i < H_; i += 256) wosh[i] = wo[i];

    const int n_glob = (lm >> 2) * 512 + w * 4 + (lm & 3);     // B^T row for frag col lm
    const u16* Bp = WhhT + (size_t)n_glob * H_ + q * 8;

    for (int t = 0; t < T_; ++t) {
        const int cur = t & 1, nxt = cur ^ 1;
        const u16* A = hb + cur * (B_ * H_);
        // ---- P1: gates GEMM (two 16-row m-tiles per wave) ----
        const u16* Ap0 = A + (size_t)(wave * 32 + lm) * H_ + q * 8;
        const u16* Ap1 = Ap0 + 16 * H_;
        floatx4 acc0 = {0.f, 0.f, 0.f, 0.f}, acc1 = {0.f, 0.f, 0.f, 0.f};
        #pragma unroll
        for (int kt = 0; kt < 16; ++kt) {
            short8 bfr = *(const short8*)(Bp + kt * 32);
            short8 a0 = *(const short8*)(Ap0 + kt * 32);
            short8 a1 = *(const short8*)(Ap1 + kt * 32);
            acc0 = __builtin_amdgcn_mfma_f32_16x16x32_bf16(a0, bfr, acc0, 0, 0, 0);
            acc1 = __builtin_amdgcn_mfma_f32_16x16x32_bf16(a1, bfr, acc1, 0, 0, 0);
        }
        const int gslot = (lm >> 2) * 512 + (lm & 3);
        #pragma unroll
        for (int r = 0; r < 4; ++r) {
            int b0 = wave * 32 + q * 4 + r;
            gl[gslot + b0 * 4] = acc0[r];
            gl[gslot + (b0 + 16) * 4] = acc1[r];
        }
        __syncthreads();
        // ---- LSTM elementwise: 512 cells (b x 4 j), 2 per thread ----
        u16* hnxt = hb + nxt * (B_ * H_);
        #pragma unroll
        for (int e = 0; e < 2; ++e) {
            int cell = tid * 2 + e;
            int b = cell >> 2, jj = cell & 3, j = w * 4 + jj;
            const float* xt = Xin + ((size_t)t * B_ + b) * (4 * H_) + j;
            float gi = gl[cell] + xt[0];
            float gf = gl[512 + cell] + xt[H_];
            float gg = gl[1024 + cell] + xt[2 * H_];
            float go = gl[1536 + cell] + xt[3 * H_];
            float cn = sigm(gf) * cs[cell] + sigm(gi) * fast_tanh(gg);
            cs[cell] = cn;
            hnxt[(size_t)b * H_ + j] = f2b(sigm(go) * fast_tanh(cn));
        }
        grid.sync();

        // ---- P23: attention for b = w ----
        const u16* hrow = hb + nxt * (B_ * H_) + (size_t)w * H_;
        for (int i = tid; i < H_; i += 256) hsh[i] = b2f(hrow[i]);
        __syncthreads();
        // ah[n] = dot(h, WhT[n,:])
        for (int n = tid; n < H_; n += 256) {
            const u16* wr = WhT + (size_t)n * H_;
            float s = 0.f;
            #pragma unroll 4
            for (int k = 0; k < H_; k += 8) {
                short8 wv = *(const short8*)(wr + k);
                #pragma unroll
                for (int e = 0; e < 8; ++e) s += hsh[k + e] * b2f((u16)wv[e]);
            }
            ash[n] = s;
        }
        __syncthreads();
        // scores
        for (int f = wave; f < F_; f += 4) {
            const u16* vp = Vprojb + ((size_t)w * F_ + f) * H_ + lane * 8;
            short8 vv = *(const short8*)vp;
            float s = 0.f;
            #pragma unroll
            for (int e = 0; e < 8; ++e) {
                int h = lane * 8 + e;
                s += wosh[h] * fast_tanh(b2f((u16)vv[e]) + ash[h]);
            }
            #pragma unroll
            for (int off = 32; off; off >>= 1) s += __shfl_xor(s, off);
            if (lane == 0) sc[f] = s;
        }
        __syncthreads();
        // softmax over F=49
        if (tid < 64) {
            float v = (tid < F_) ? sc[tid] : -1e30f;
            float m = v;
            #pragma unroll
            for (int off = 32; off; off >>= 1) m = fmaxf(m, __shfl_xor(m, off));
            float e = (tid < F_) ? __expf(v - m) : 0.f;
            float sum = e;
            #pragma unroll
            for (int off = 32; off; off >>= 1) sum += __shfl_xor(sum, off);
            if (tid < F_) sc[tid] = e / sum;
        }
        __syncthreads();
        // attended + Hcat row
        const size_t rowo = ((size_t)w * T_ + t) * (2 * H_);
        for (int h = tid; h < H_; h += 256) {
            const u16* fp = feat + (size_t)w * F_ * H_ + h;
            float acc = 0.f;
            #pragma unroll
            for (int f = 0; f < F_; ++f) acc += b2f(fp[f * H_]) * sc[f];
            Hcat[rowo + h] = hrow[h];
            Hcat[rowo + H_ + h] = f2b(acc);
        }
        __syncthreads();   // protect hsh/ash/sc before next step reuses them
    }
}

// ========== m97-style bf16 MFMA GEMM: C[M,N] = A[M,K] @ Bt[N,K]^T (+bias) ==========
template <int WRITE_BF16>
__global__ __launch_bounds__(256) void gemm2(const u16* __restrict__ A, int lda,
                                             const u16* __restrict__ Bt, int ldb,
                                             void* __restrict__ Cout, int ldc,
                                             const float* __restrict__ bias1,
                                             const float* __restrict__ bias2,
                                             int M, int N, int K) {
    __shared__ __align__(16) u16 As[128 * 32];
    __shared__ __align__(16) u16 Bs[128 * 32];
    const int tid = threadIdx.x, wave = tid >> 6, lane = tid & 63;
    const int wr = wave >> 1, wc = wave & 1;
    const int lm = lane & 15, q = lane >> 4;
    const int m0 = blockIdx.x * 128, n0 = blockIdx.y * 128;

    const int off = wave * 1024 + lane * 16;
    const int r0 = off >> 6;
    const int c0 = (off & 63) >> 1;

    const u16* gA0 = A + (size_t)(m0 + r0) * lda + c0;
    const u16* gA1 = A + (size_t)(m0 + r0 + 64) * lda + c0;
    int nb0 = n0 + r0;      if (nb0 > N - 1) nb0 = N - 1;
    int nb1 = n0 + r0 + 64; if (nb1 > N - 1) nb1 = N - 1;
    const u16* gB0 = Bt + (size_t)nb0 * ldb + c0;
    const u16* gB1 = Bt + (size_t)nb1 * ldb + c0;
    char* lA0 = (char*)As + wave * 1024;
    char* lA1 = (char*)As + 4096 + wave * 1024;
    char* lB0 = (char*)Bs + wave * 1024;
    char* lB1 = (char*)Bs + 4096 + wave * 1024;

    floatx4 acc[4][4];
    #pragma unroll
    for (int i = 0; i < 4; ++i)
        #pragma unroll
        for (int j = 0; j < 4; ++j) acc[i][j] = floatx4{0.f, 0.f, 0.f, 0.f};

    const int nkt = K >> 5;
    for (int kt = 0; kt < nkt; ++kt) {
        const int ko = kt * 32;
        load_lds16(gA0 + ko, lA0);
        load_lds16(gA1 + ko, lA1);
        load_lds16(gB0 + ko, lB0);
        load_lds16(gB1 + ko, lB1);
        __syncthreads();
        short8 af[4], bf[4];
        #pragma unroll
        for (int i = 0; i < 4; ++i)
            af[i] = *(const short8*)&As[(wr * 64 + i * 16 + lm) * 32 + q * 8];
        #pragma unroll
        for (int j = 0; j < 4; ++j)
            bf[j] = *(const short8*)&Bs[(wc * 64 + j * 16 + lm) * 32 + q * 8];
        #pragma unroll
        for (int i = 0; i < 4; ++i)
            #pragma unroll
            for (int j = 0; j < 4; ++j)
                acc[i][j] = __builtin_amdgcn_mfma_f32_16x16x32_bf16(af[i], bf[j], acc[i][j], 0, 0, 0);
        __syncthreads();
    }

    #pragma unroll
    for (int i = 0; i < 4; ++i) {
        const int row = m0 + wr * 64 + i * 16 + q * 4;
        #pragma unroll
        for (int j = 0; j < 4; ++j) {
            const int col = n0 + wc * 64 + j * 16 + lm;
            if (col < N) {
                #pragma unroll
                for (int r = 0; r < 4; ++r) {
                    float v = acc[i][j][r];
                    if (bias1) v += bias1[col];
                    if (bias2) v += bias2[col];
                    if (WRITE_BF16) ((u16*)Cout)[(size_t)(row + r) * ldc + col] = f2b(v);
                    else            ((float*)Cout)[(size_t)(row + r) * ldc + col] = v;
                }
            }
        }
    }
}

extern "C" void kernel_launch(void* const* d_in, const int* in_sizes, int n_in,
                              void* d_out, int out_size, void* d_ws, size_t ws_size,
                              hipStream_t stream) {
    const int*   cap   = (const int*)d_in[0];
    const float* gf    = (const float*)d_in[1];
    const float* area  = (const float*)d_in[2];
    const float* h0    = (const float*)d_in[3];
    const float* c0    = (const float*)d_in[4];
    const float* emb   = (const float*)d_in[5];
    const float* W_ih  = (const float*)d_in[6];
    const float* W_hh  = (const float*)d_in[7];
    const float* b_ih  = (const float*)d_in[8];
    const float* b_hh  = (const float*)d_in[9];
    const float* Wv    = (const float*)d_in[10];
    const float* Wh    = (const float*)d_in[11];
    const float* wo    = (const float*)d_in[12];
    const float* W_out = (const float*)d_in[13];
    const float* b_out = (const float*)d_in[14];
    float* out = (float*)d_out;

    char* p = (char*)d_ws;
    auto alloc = [&](size_t bytes) {
        char* q = p;
        p += (bytes + 255) & ~(size_t)255;
        return q;
    };
    u16*   X      = (u16*)alloc((size_t)T_ * B_ * 2 * H_ * 2);
    u16*   WihT   = (u16*)alloc((size_t)4 * H_ * 2 * H_ * 2);
    u16*   WhhT   = (u16*)alloc((size_t)4 * H_ * H_ * 2);
    u16*   WvT    = (u16*)alloc((size_t)H_ * H_ * 2);
    u16*   WhT    = (u16*)alloc((size_t)H_ * H_ * 2);
    u16*   WoutT  = (u16*)alloc((size_t)V_ * 2 * H_ * 2);
    u16*   feat   = (u16*)alloc((size_t)B_ * F_ * H_ * 2);
    float* Xin    = (float*)alloc((size_t)T_ * B_ * 4 * H_ * 4);
    u16*   Vprojb = (u16*)alloc((size_t)B_ * F_ * H_ * 2);
    u16*   hb     = (u16*)alloc((size_t)2 * B_ * H_ * 2);
    u16*   Hcat   = (u16*)alloc((size_t)B_ * T_ * 2 * H_ * 2);

    // 1) all setup in one kernel
    prep<<<28960, 256, 0, stream>>>(W_ih, WihT, W_hh, WhhT, Wv, WvT, Wh, WhT,
                                    W_out, WoutT, cap, emb, gf, X, area, feat,
                                    h0, hb);
    // 2) Xin = X @ W_ih + b_ih + b_hh   [2560,2048] f32
    gemm2<0><<<dim3(T_ * B_ / 128, 4 * H_ / 128), 256, 0, stream>>>(
        X, 2 * H_, WihT, 2 * H_, Xin, 4 * H_, b_ih, b_hh, T_ * B_, 4 * H_, 2 * H_);
    // 3) Vproj = feat @ Wv -> bf16 [6272,512]
    gemm2<1><<<dim3(B_ * F_ / 128, H_ / 128), 256, 0, stream>>>(
        feat, H_, WvT, H_, Vprojb, H_, nullptr, nullptr, B_ * F_, H_, H_);
    // 4) the whole recurrence in one cooperative launch (grid.sync inside)
    void* ka[] = {(void*)&WhhT, (void*)&WhT, (void*)&Vprojb, (void*)&wo,
                  (void*)&feat, (void*)&Xin, (void*)&c0, (void*)&hb, (void*)&Hcat};
    hipLaunchCooperativeKernel((void*)seq_loop, dim3(NWG), dim3(256), ka, 0, stream);
    // 5) out = Hcat @ W_out + b_out   [2560,10000] f32
    gemm2<0><<<dim3(T_ * B_ / 128, (V_ + 127) / 128), 256, 0, stream>>>(
        Hcat, 2 * H_, WoutT, 2 * H_, out, V_, b_out, nullptr, T_ * B_, V_, 2 * H_);
}